// Round 2
// baseline (756.724 us; speedup 1.0000x reference)
//
#include <hip/hip_runtime.h>
#include <math.h>

#define B 64
#define Q 300
#define PARTS 6
#define D 256
#define NHEAD 8
#define DHEAD 32
#define FF 512
#define NLAYERS 2
#define NCLS 396
#define L_TOK 10   // PARTS + 4 image tokens

// ---------------------------------------------------------------------------
// K1: global average pool of feat0..3 over spatial dims -> pooled[B][4][D]
// one block per (scale, b, d) row; row is contiguous s*s floats.
// (802 MB of reads -> HBM-bound; measured ~80% of peak already)
// ---------------------------------------------------------------------------
__global__ __launch_bounds__(256) void pool_kernel(
    const float* __restrict__ f0, const float* __restrict__ f1,
    const float* __restrict__ f2, const float* __restrict__ f3,
    float* __restrict__ pooled)
{
    int bid = blockIdx.x;
    int scale = bid >> 14;          // 16384 rows per scale (B*D)
    int r = bid & 16383;
    int b = r >> 8;
    int d = r & 255;
    const float* src;
    int n;
    switch (scale) {
        case 0: src = f0; n = 96 * 96; break;
        case 1: src = f1; n = 48 * 48; break;
        case 2: src = f2; n = 24 * 24; break;
        default: src = f3; n = 12 * 12; break;
    }
    const float4* p4 = reinterpret_cast<const float4*>(src + ((size_t)b * D + d) * (size_t)n);
    int n4 = n >> 2;
    float s = 0.f;
    for (int i = threadIdx.x; i < n4; i += 256) {
        float4 v = p4[i];
        s += v.x + v.y + v.z + v.w;
    }
    for (int off = 32; off; off >>= 1) s += __shfl_down(s, off, 64);
    __shared__ float red[4];
    int wid = threadIdx.x >> 6;
    int lane = threadIdx.x & 63;
    if (lane == 0) red[wid] = s;
    __syncthreads();
    if (threadIdx.x == 0) {
        float t = red[0] + red[1] + red[2] + red[3];
        pooled[((size_t)b * 4 + scale) * D + d] = t / (float)n;
    }
}

// ---------------------------------------------------------------------------
// K2: fused {cls masked-mean pool + img token proj + 2-layer transformer +
// masked pool + classifier}. One 1024-thread block per batch element.
// tx = tid&255 owns a feature column; ty = tid>>8 splits token rows
// (r = ty, ty+4, ty+8) so 16 waves/CU = 4 waves/SIMD hide latency.
// All xs/h1 LDS reads are wave-uniform broadcasts (no bank conflicts).
// ---------------------------------------------------------------------------
__global__ __launch_bounds__(1024) void transformer_kernel(
    const float* __restrict__ pred, const float* __restrict__ hs,
    const float* __restrict__ pooled,
    const float* __restrict__ ipw, const float* __restrict__ ipb,
    const float* __restrict__ in_w, const float* __restrict__ in_b,
    const float* __restrict__ out_w, const float* __restrict__ out_b,
    const float* __restrict__ l1w, const float* __restrict__ l1b,
    const float* __restrict__ l2w, const float* __restrict__ l2b,
    const float* __restrict__ ln1w, const float* __restrict__ ln1b,
    const float* __restrict__ ln2w, const float* __restrict__ ln2b,
    const float* __restrict__ c1w, const float* __restrict__ c1b,
    const float* __restrict__ c2w, const float* __restrict__ c2b,
    float* __restrict__ out)
{
    const int b = blockIdx.x;
    const int tid = threadIdx.x;
    const int tx = tid & 255;
    const int ty = tid >> 8;

    __shared__ float xs[L_TOK * D];       // 2560: current x (tokens)
    __shared__ float qkvS[L_TOK * 768];   // 7680: qkv / residual xr / csum partials
    __shared__ float tmpS[L_TOK * FF];    // 5120: maskL / pld / ao / sc / h1 / cls tmps
    __shared__ float biasK[16];
    __shared__ float rowst[20];           // [0..10) mean, [10..20) rstd
    __shared__ float countsS[8];

    float* maskL = tmpS;                  // [1800]
    float* pldS  = tmpS + 2048;           // [1024]
    float* xr = qkvS;                     // [2560] residual buffer
    float* ao = tmpS;                     // [2560]
    float* sc = tmpS + 2560;              // [800]
    float* h1 = tmpS;                     // [5120]

    // ================= prologue: masks + pooled stage =================
    pldS[tid] = pooled[(size_t)b * 1024 + tid];
    for (int i = tid; i < Q * PARTS; i += 1024) {
        float x = pred[(size_t)b * Q * PARTS + i];
        float sg = 1.f / (1.f + expf(-x));
        maskL[i] = (sg > 0.3f) ? 1.f : 0.f;
    }
    __syncthreads();

    // counts: wave w (<6) reduces part w
    {
        int wid = tid >> 6, lane = tid & 63;
        if (wid < PARTS) {
            float c = 0.f;
            for (int q = lane; q < Q; q += 64) c += maskL[q * PARTS + wid];
            for (int off = 32; off; off >>= 1) c += __shfl_down(c, off, 64);
            if (lane == 0) countsS[wid] = c;
        }
    }
    // csum partials: ty splits the 300 queries into 4x75
    {
        float acc[PARTS] = {0.f, 0.f, 0.f, 0.f, 0.f, 0.f};
        const float* hsq = hs + ((size_t)b * Q + ty * 75) * D + tx;
        for (int q = 0; q < 75; q++) {
            float h = hsq[(size_t)q * D];
            #pragma unroll
            for (int p = 0; p < PARTS; p++)
                acc[p] += maskL[(ty * 75 + q) * PARTS + p] * h;
        }
        #pragma unroll
        for (int p = 0; p < PARTS; p++)
            qkvS[ty * 1536 + p * 256 + tx] = acc[p];
    }
    __syncthreads();

    bool anyv = (countsS[0] > 0.f) || (countsS[1] > 0.f) || (countsS[2] > 0.f)
             || (countsS[3] > 0.f) || (countsS[4] > 0.f) || (countsS[5] > 0.f);

    // cmean -> xs rows 0..5 (with slot-0 fallback)
    for (int o = tid; o < PARTS * D; o += 1024) {
        int p = o >> 8;
        float s = qkvS[o] + qkvS[1536 + o] + qkvS[3072 + o] + qkvS[4608 + o];
        float cm = s / fmaxf(countsS[p], 1.f);
        if (p == 0 && !anyv) cm = hs[(size_t)b * Q * D + (o & 255)];
        xs[o] = cm;
    }
    // img tokens -> xs rows 6..9 (i = ty, c = tx)
    {
        const float4* w4 = reinterpret_cast<const float4*>(ipw + ((size_t)ty * D + tx) * D);
        const float* prow = &pldS[ty * D];
        float acc = 0.f;
        #pragma unroll 4
        for (int k4 = 0; k4 < D / 4; k4++) {
            float4 wv = w4[k4];
            int k = k4 * 4;
            acc += wv.x * prow[k] + wv.y * prow[k + 1] + wv.z * prow[k + 2] + wv.w * prow[k + 3];
        }
        xs[(6 + ty) * D + tx] = acc + ipb[ty * D + tx];
    }
    if (tid < L_TOK) {
        float bv = 0.f;
        if (tid < PARTS) {
            bool v = countsS[tid] > 0.f;
            if (tid == 0 && !anyv) v = true;
            bv = v ? 0.f : -1e30f;
        }
        biasK[tid] = bv;
    }
    __syncthreads();

    const float4* xs4 = reinterpret_cast<const float4*>(xs);

    // ================= 2-layer encoder =================
    for (int l = 0; l < NLAYERS; l++) {
        // ---- QKV: qkv[r][c] = x[r].in_w[c] + b ; c = tx + 256j, r = ty+4ri
        {
            float acc[3][3];
            #pragma unroll
            for (int j = 0; j < 3; j++)
                #pragma unroll
                for (int ri = 0; ri < 3; ri++) acc[j][ri] = 0.f;
            const float4* w0 = reinterpret_cast<const float4*>(in_w + ((size_t)l * 768 + tx) * D);
            const float4* w1 = reinterpret_cast<const float4*>(in_w + ((size_t)l * 768 + tx + 256) * D);
            const float4* w2 = reinterpret_cast<const float4*>(in_w + ((size_t)l * 768 + tx + 512) * D);
            #pragma unroll 2
            for (int k4 = 0; k4 < D / 4; k4++) {
                float4 a0 = w0[k4], a1 = w1[k4], a2 = w2[k4];
                #pragma unroll
                for (int ri = 0; ri < 3; ri++) {
                    int r = ty + 4 * ri;
                    if (r < L_TOK) {
                        float4 xv = xs4[r * (D / 4) + k4];
                        acc[0][ri] += a0.x * xv.x + a0.y * xv.y + a0.z * xv.z + a0.w * xv.w;
                        acc[1][ri] += a1.x * xv.x + a1.y * xv.y + a1.z * xv.z + a1.w * xv.w;
                        acc[2][ri] += a2.x * xv.x + a2.y * xv.y + a2.z * xv.z + a2.w * xv.w;
                    }
                }
            }
            #pragma unroll
            for (int j = 0; j < 3; j++) {
                int c = tx + j * 256;
                float bb = in_b[l * 768 + c];
                #pragma unroll
                for (int ri = 0; ri < 3; ri++) {
                    int r = ty + 4 * ri;
                    if (r < L_TOK) qkvS[r * 768 + c] = acc[j][ri] + bb;
                }
            }
        }
        __syncthreads();

        // ---- scores + bias (800 dots of length 32)
        const float scale = 0.17677669529663687f;  // 1/sqrt(32)
        if (tid < NHEAD * L_TOK * L_TOK) {
            int h = tid / (L_TOK * L_TOK);
            int rem = tid - h * (L_TOK * L_TOK);
            int qr = rem / L_TOK;
            int kr = rem - qr * L_TOK;
            const float* qp = &qkvS[qr * 768 + h * DHEAD];
            const float* kp = &qkvS[kr * 768 + 256 + h * DHEAD];
            float s = 0.f;
            #pragma unroll
            for (int dh = 0; dh < DHEAD; dh++) s += qp[dh] * kp[dh];
            sc[tid] = s * scale + biasK[kr];
        }
        __syncthreads();

        // ---- softmax over keys (80 rows)
        if (tid < NHEAD * L_TOK) {
            float* row = &sc[tid * L_TOK];
            float m = row[0];
            #pragma unroll
            for (int k = 1; k < L_TOK; k++) m = fmaxf(m, row[k]);
            float ssum = 0.f;
            #pragma unroll
            for (int k = 0; k < L_TOK; k++) { float e = expf(row[k] - m); row[k] = e; ssum += e; }
            float inv = 1.f / ssum;
            #pragma unroll
            for (int k = 0; k < L_TOK; k++) row[k] *= inv;
        }
        __syncthreads();

        // ---- attn @ V -> ao[r][c]
        {
            int h = tx >> 5;
            #pragma unroll
            for (int ri = 0; ri < 3; ri++) {
                int r = ty + 4 * ri;
                if (r < L_TOK) {
                    float s = 0.f;
                    #pragma unroll
                    for (int kr = 0; kr < L_TOK; kr++)
                        s += sc[h * 100 + r * L_TOK + kr] * qkvS[kr * 768 + 512 + tx];
                    ao[r * D + tx] = s;
                }
            }
        }
        __syncthreads();

        // ---- out_proj + residual -> xr (aliases qkvS; V reads done)
        {
            float acc[3] = {0.f, 0.f, 0.f};
            const float4* w4 = reinterpret_cast<const float4*>(out_w + ((size_t)l * D + tx) * D);
            const float4* ao4 = reinterpret_cast<const float4*>(ao);
            #pragma unroll 2
            for (int k4 = 0; k4 < D / 4; k4++) {
                float4 wv = w4[k4];
                #pragma unroll
                for (int ri = 0; ri < 3; ri++) {
                    int r = ty + 4 * ri;
                    if (r < L_TOK) {
                        float4 av = ao4[r * (D / 4) + k4];
                        acc[ri] += wv.x * av.x + wv.y * av.y + wv.z * av.z + wv.w * av.w;
                    }
                }
            }
            float bb = out_b[l * D + tx];
            __syncthreads();   // all ao/V reads done before overwriting qkvS
            #pragma unroll
            for (int ri = 0; ri < 3; ri++) {
                int r = ty + 4 * ri;
                if (r < L_TOK) xr[r * D + tx] = xs[r * D + tx] + acc[ri] + bb;
            }
        }
        __syncthreads();

        // ---- LN1: xr -> xs
        {
            int wid = tid >> 6, lane = tid & 63;
            if (wid < L_TOK) {
                float s = 0.f, s2 = 0.f;
                for (int j = lane; j < D; j += 64) {
                    float v = xr[wid * D + j];
                    s += v; s2 += v * v;
                }
                for (int off = 32; off; off >>= 1) {
                    s += __shfl_down(s, off, 64);
                    s2 += __shfl_down(s2, off, 64);
                }
                if (lane == 0) {
                    float m = s * (1.f / D);
                    float var = s2 * (1.f / D) - m * m;
                    rowst[wid] = m;
                    rowst[10 + wid] = rsqrtf(fmaxf(var, 0.f) + 1e-5f);
                }
            }
            __syncthreads();
            const float* w = ln1w + l * D;
            const float* bc = ln1b + l * D;
            for (int i = tid; i < L_TOK * D; i += 1024) {
                int r = i >> 8, c = i & 255;
                xs[i] = (xr[i] - rowst[r]) * rowst[10 + r] * w[c] + bc[c];
            }
        }
        __syncthreads();

        // ---- FF1: h1[r][f] = relu(x[r].l1w[f] + b), f = tx + 256j
        {
            float acc[2][3];
            #pragma unroll
            for (int j = 0; j < 2; j++)
                #pragma unroll
                for (int ri = 0; ri < 3; ri++) acc[j][ri] = 0.f;
            const float4* w0 = reinterpret_cast<const float4*>(l1w + ((size_t)l * FF + tx) * D);
            const float4* w1 = reinterpret_cast<const float4*>(l1w + ((size_t)l * FF + tx + 256) * D);
            #pragma unroll 2
            for (int k4 = 0; k4 < D / 4; k4++) {
                float4 a0 = w0[k4], a1 = w1[k4];
                #pragma unroll
                for (int ri = 0; ri < 3; ri++) {
                    int r = ty + 4 * ri;
                    if (r < L_TOK) {
                        float4 xv = xs4[r * (D / 4) + k4];
                        acc[0][ri] += a0.x * xv.x + a0.y * xv.y + a0.z * xv.z + a0.w * xv.w;
                        acc[1][ri] += a1.x * xv.x + a1.y * xv.y + a1.z * xv.z + a1.w * xv.w;
                    }
                }
            }
            __syncthreads();   // ao/sc region dead; safe to write h1
            #pragma unroll
            for (int j = 0; j < 2; j++) {
                int f = tx + j * 256;
                float bb = l1b[l * FF + f];
                #pragma unroll
                for (int ri = 0; ri < 3; ri++) {
                    int r = ty + 4 * ri;
                    if (r < L_TOK) h1[r * FF + f] = fmaxf(acc[j][ri] + bb, 0.f);
                }
            }
        }
        __syncthreads();

        // ---- FF2 + residual -> xr
        {
            float acc[3] = {0.f, 0.f, 0.f};
            const float4* w4 = reinterpret_cast<const float4*>(l2w + ((size_t)l * D + tx) * FF);
            const float4* h14 = reinterpret_cast<const float4*>(h1);
            #pragma unroll 2
            for (int k4 = 0; k4 < FF / 4; k4++) {
                float4 wv = w4[k4];
                #pragma unroll
                for (int ri = 0; ri < 3; ri++) {
                    int r = ty + 4 * ri;
                    if (r < L_TOK) {
                        float4 hv = h14[r * (FF / 4) + k4];
                        acc[ri] += wv.x * hv.x + wv.y * hv.y + wv.z * hv.z + wv.w * hv.w;
                    }
                }
            }
            float bb = l2b[l * D + tx];
            #pragma unroll
            for (int ri = 0; ri < 3; ri++) {
                int r = ty + 4 * ri;
                if (r < L_TOK) xr[r * D + tx] = xs[r * D + tx] + acc[ri] + bb;
            }
        }
        __syncthreads();

        // ---- LN2: xr -> xs
        {
            int wid = tid >> 6, lane = tid & 63;
            if (wid < L_TOK) {
                float s = 0.f, s2 = 0.f;
                for (int j = lane; j < D; j += 64) {
                    float v = xr[wid * D + j];
                    s += v; s2 += v * v;
                }
                for (int off = 32; off; off >>= 1) {
                    s += __shfl_down(s, off, 64);
                    s2 += __shfl_down(s2, off, 64);
                }
                if (lane == 0) {
                    float m = s * (1.f / D);
                    float var = s2 * (1.f / D) - m * m;
                    rowst[wid] = m;
                    rowst[10 + wid] = rsqrtf(fmaxf(var, 0.f) + 1e-5f);
                }
            }
            __syncthreads();
            const float* w = ln2w + l * D;
            const float* bc = ln2b + l * D;
            for (int i = tid; i < L_TOK * D; i += 1024) {
                int r = i >> 8, c = i & 255;
                xs[i] = (xr[i] - rowst[r]) * rowst[10 + r] * w[c] + bc[c];
            }
        }
        __syncthreads();
    }

    // ================= epilogue =================
    float* ct    = tmpS;           // [256]
    float* clsP  = tmpS + 512;     // [1024] cls1 K-split partials
    float* hbuf  = tmpS + 1536;    // [512]
    float* cls2P = tmpS + 2048;    // [792]

    // masked mean pool over valid tokens
    if (tid < D) {
        float len = 0.f, s = 0.f;
        #pragma unroll
        for (int r = 0; r < L_TOK; r++) {
            float v = (biasK[r] == 0.f) ? 1.f : 0.f;
            len += v;
            s += v * xs[r * D + tid];
        }
        ct[tid] = s / fmaxf(len, 1.f);
    }
    __syncthreads();

    // cls1: 512 outputs, K=256 split in 2 halves across kh = tid>>9
    {
        int c = tid & 511, kh = tid >> 9;
        const float4* w4 = reinterpret_cast<const float4*>(c1w + (size_t)c * D + kh * 128);
        const float4* ct4 = reinterpret_cast<const float4*>(ct + kh * 128);
        float acc = 0.f;
        #pragma unroll 4
        for (int k4 = 0; k4 < 32; k4++) {
            float4 wv = w4[k4];
            float4 xv = ct4[k4];
            acc += wv.x * xv.x + wv.y * xv.y + wv.z * xv.z + wv.w * xv.w;
        }
        clsP[kh * 512 + c] = acc;
    }
    __syncthreads();
    if (tid < 512) hbuf[tid] = fmaxf(clsP[tid] + clsP[512 + tid] + c1b[tid], 0.f);
    __syncthreads();

    // cls2: 396 outputs, K=512 split in 2 halves
    {
        int o = tid & 511, kh = tid >> 9;
        if (o < NCLS) {
            const float4* w4 = reinterpret_cast<const float4*>(c2w + (size_t)o * FF + kh * 256);
            const float4* h4 = reinterpret_cast<const float4*>(hbuf + kh * 256);
            float acc = 0.f;
            #pragma unroll 4
            for (int k4 = 0; k4 < 64; k4++) {
                float4 wv = w4[k4];
                float4 hv = h4[k4];
                acc += wv.x * hv.x + wv.y * hv.y + wv.z * hv.z + wv.w * hv.w;
            }
            cls2P[kh * NCLS + o] = acc;
        }
    }
    __syncthreads();
    if (tid < NCLS) out[(size_t)b * NCLS + tid] = cls2P[tid] + cls2P[NCLS + tid] + c2b[tid];
}

// ---------------------------------------------------------------------------
extern "C" void kernel_launch(void* const* d_in, const int* in_sizes, int n_in,
                              void* d_out, int out_size, void* d_ws, size_t ws_size,
                              hipStream_t stream)
{
    const float* pred = (const float*)d_in[0];
    const float* hs   = (const float*)d_in[1];
    const float* f0   = (const float*)d_in[2];
    const float* f1   = (const float*)d_in[3];
    const float* f2   = (const float*)d_in[4];
    const float* f3   = (const float*)d_in[5];
    const float* ipw  = (const float*)d_in[6];
    const float* ipb  = (const float*)d_in[7];
    const float* inw  = (const float*)d_in[8];
    const float* inb  = (const float*)d_in[9];
    const float* ow   = (const float*)d_in[10];
    const float* ob   = (const float*)d_in[11];
    const float* l1w  = (const float*)d_in[12];
    const float* l1b  = (const float*)d_in[13];
    const float* l2w  = (const float*)d_in[14];
    const float* l2b  = (const float*)d_in[15];
    const float* ln1w = (const float*)d_in[16];
    const float* ln1b = (const float*)d_in[17];
    const float* ln2w = (const float*)d_in[18];
    const float* ln2b = (const float*)d_in[19];
    const float* c1w  = (const float*)d_in[20];
    const float* c1b  = (const float*)d_in[21];
    const float* c2w  = (const float*)d_in[22];
    const float* c2b  = (const float*)d_in[23];

    float* pooled = (float*)d_ws;   // B*4*D = 65536 floats

    pool_kernel<<<4 * B * D, 256, 0, stream>>>(f0, f1, f2, f3, pooled);
    transformer_kernel<<<B, 1024, 0, stream>>>(
        pred, hs, pooled, ipw, ipb, inw, inb, ow, ob, l1w, l1b, l2w, l2b,
        ln1w, ln1b, ln2w, ln2b, c1w, c1b, c2w, c2b, (float*)d_out);
}

// Round 3
// 530.835 us; speedup vs baseline: 1.4255x; 1.4255x over previous
//
#include <hip/hip_runtime.h>
#include <math.h>

#define B 64
#define Q 300
#define PARTS 6
#define D 256
#define NHEAD 8
#define DHEAD 32
#define FF 512
#define NLAYERS 2
#define NCLS 396
#define L_TOK 10

// ---------------------------------------------------------------------------
// K1: global average pool of feat0..3 -> pooled[B][4][D]. HBM-bound (~127us).
// ---------------------------------------------------------------------------
__global__ __launch_bounds__(256) void pool_kernel(
    const float* __restrict__ f0, const float* __restrict__ f1,
    const float* __restrict__ f2, const float* __restrict__ f3,
    float* __restrict__ pooled)
{
    int bid = blockIdx.x;
    int scale = bid >> 14;          // 16384 rows (B*D) per scale
    int r = bid & 16383;
    int b = r >> 8;
    int d = r & 255;
    const float* src;
    int n;
    switch (scale) {
        case 0: src = f0; n = 96 * 96; break;
        case 1: src = f1; n = 48 * 48; break;
        case 2: src = f2; n = 24 * 24; break;
        default: src = f3; n = 12 * 12; break;
    }
    const float4* p4 = reinterpret_cast<const float4*>(src + ((size_t)b * D + d) * (size_t)n);
    int n4 = n >> 2;
    float s = 0.f;
    for (int i = threadIdx.x; i < n4; i += 256) {
        float4 v = p4[i];
        s += v.x + v.y + v.z + v.w;
    }
    for (int off = 32; off; off >>= 1) s += __shfl_down(s, off, 64);
    __shared__ float red[4];
    int wid = threadIdx.x >> 6;
    int lane = threadIdx.x & 63;
    if (lane == 0) red[wid] = s;
    __syncthreads();
    if (threadIdx.x == 0) {
        float t = red[0] + red[1] + red[2] + red[3];
        pooled[((size_t)b * 4 + scale) * D + d] = t / (float)n;
    }
}

// ---------------------------------------------------------------------------
// K2: prologue -> tokens xA[B,10,256] + key-padding bias biasG[B,10]
// grid B, 1024 threads (proven correct in R2).
// ---------------------------------------------------------------------------
__global__ __launch_bounds__(1024) void prologue_kernel(
    const float* __restrict__ pred, const float* __restrict__ hs,
    const float* __restrict__ pooled,
    const float* __restrict__ ipw, const float* __restrict__ ipb,
    float* __restrict__ xA, float* __restrict__ biasG)
{
    const int b = blockIdx.x;
    const int tid = threadIdx.x;
    const int tx = tid & 255;
    const int ty = tid >> 8;

    __shared__ float maskL[Q * PARTS];   // 1800
    __shared__ float pldS[1024];
    __shared__ float csum[4 * PARTS * D]; // 6144
    __shared__ float countsS[8];

    pldS[tid] = pooled[(size_t)b * 1024 + tid];
    for (int i = tid; i < Q * PARTS; i += 1024) {
        float x = pred[(size_t)b * Q * PARTS + i];
        float sg = 1.f / (1.f + expf(-x));
        maskL[i] = (sg > 0.3f) ? 1.f : 0.f;
    }
    __syncthreads();

    {
        int wid = tid >> 6, lane = tid & 63;
        if (wid < PARTS) {
            float c = 0.f;
            for (int q = lane; q < Q; q += 64) c += maskL[q * PARTS + wid];
            for (int off = 32; off; off >>= 1) c += __shfl_down(c, off, 64);
            if (lane == 0) countsS[wid] = c;
        }
    }
    {
        float acc[PARTS] = {0.f, 0.f, 0.f, 0.f, 0.f, 0.f};
        const float* hsq = hs + ((size_t)b * Q + ty * 75) * D + tx;
        for (int q = 0; q < 75; q++) {
            float h = hsq[(size_t)q * D];
            #pragma unroll
            for (int p = 0; p < PARTS; p++)
                acc[p] += maskL[(ty * 75 + q) * PARTS + p] * h;
        }
        #pragma unroll
        for (int p = 0; p < PARTS; p++)
            csum[ty * 1536 + p * 256 + tx] = acc[p];
    }
    __syncthreads();

    bool anyv = (countsS[0] > 0.f) || (countsS[1] > 0.f) || (countsS[2] > 0.f)
             || (countsS[3] > 0.f) || (countsS[4] > 0.f) || (countsS[5] > 0.f);

    for (int o = tid; o < PARTS * D; o += 1024) {
        int p = o >> 8;
        float s = csum[o] + csum[1536 + o] + csum[3072 + o] + csum[4608 + o];
        float cm = s / fmaxf(countsS[p], 1.f);
        if (p == 0 && !anyv) cm = hs[(size_t)b * Q * D + (o & 255)];
        xA[(size_t)b * L_TOK * D + o] = cm;
    }
    {   // img token i = ty
        const float4* w4 = reinterpret_cast<const float4*>(ipw + ((size_t)ty * D + tx) * D);
        const float* prow = &pldS[ty * D];
        float acc = 0.f;
        #pragma unroll 4
        for (int k4 = 0; k4 < D / 4; k4++) {
            float4 wv = w4[k4];
            int k = k4 * 4;
            acc += wv.x * prow[k] + wv.y * prow[k + 1] + wv.z * prow[k + 2] + wv.w * prow[k + 3];
        }
        xA[(size_t)b * L_TOK * D + (6 + ty) * D + tx] = acc + ipb[ty * D + tx];
    }
    if (tid < L_TOK) {
        float bv = 0.f;
        if (tid < PARTS) {
            bool v = countsS[tid] > 0.f;
            if (tid == 0 && !anyv) v = true;
            bv = v ? 0.f : -1e30f;
        }
        biasG[b * L_TOK + tid] = bv;
    }
}

// ---------------------------------------------------------------------------
// K3: attention for one (b, head): qkv proj + scores + softmax + AV -> aoG
// grid B*NHEAD = 512, 256 threads.
// w = in_proj_w + l*768*256 ; bias = in_proj_b + l*768
// ---------------------------------------------------------------------------
__global__ __launch_bounds__(256) void attn_kernel(
    const float* __restrict__ xin, const float* __restrict__ biasG,
    const float* __restrict__ w, const float* __restrict__ bias,
    float* __restrict__ aoG)
{
    const int blk = blockIdx.x;
    const int b = blk >> 3;
    const int h = blk & 7;
    const int tid = threadIdx.x;

    __shared__ float xsh[L_TOK * D];   // 2560
    __shared__ float qs[L_TOK * 96];   // 960: q|k|v slices for this head
    __shared__ float sc[100];

    for (int i = tid; i < L_TOK * D; i += 256)
        xsh[i] = xin[(size_t)b * L_TOK * D + i];
    __syncthreads();

    const float4* xsh4 = reinterpret_cast<const float4*>(xsh);
    #pragma unroll
    for (int jj = 0; jj < 4; jj++) {
        int idx = jj * 256 + tid;
        if (idx < 960) {
            int r = idx / 96;
            int cm = idx - 96 * r;
            int m = cm >> 5;               // 0=q 1=k 2=v
            int c = cm & 31;
            int row = m * 256 + h * 32 + c;
            const float4* w4 = reinterpret_cast<const float4*>(w + (size_t)row * D);
            float acc = 0.f;
            #pragma unroll 4
            for (int k4 = 0; k4 < D / 4; k4++) {
                float4 wv = w4[k4];
                float4 xv = xsh4[r * 64 + k4];
                acc += wv.x * xv.x + wv.y * xv.y + wv.z * xv.z + wv.w * xv.w;
            }
            qs[r * 96 + cm] = acc + bias[row];
        }
    }
    __syncthreads();

    if (tid < 100) {
        int qr = tid / 10, kr = tid - 10 * qr;
        float s = 0.f;
        #pragma unroll
        for (int dh = 0; dh < DHEAD; dh++)
            s += qs[qr * 96 + dh] * qs[kr * 96 + 32 + dh];
        sc[tid] = s * 0.17677669529663687f + biasG[b * L_TOK + kr];
    }
    __syncthreads();

    if (tid < L_TOK) {
        float* row = &sc[tid * 10];
        float m = row[0];
        #pragma unroll
        for (int k = 1; k < 10; k++) m = fmaxf(m, row[k]);
        float ss = 0.f;
        #pragma unroll
        for (int k = 0; k < 10; k++) { float e = expf(row[k] - m); row[k] = e; ss += e; }
        float inv = 1.f / ss;
        #pragma unroll
        for (int k = 0; k < 10; k++) row[k] *= inv;
    }
    __syncthreads();

    #pragma unroll
    for (int jj = 0; jj < 2; jj++) {
        int idx = jj * 256 + tid;
        if (idx < 320) {
            int r = idx >> 5, c = idx & 31;
            float s = 0.f;
            #pragma unroll
            for (int kr = 0; kr < 10; kr++)
                s += sc[r * 10 + kr] * qs[kr * 96 + 64 + c];
            aoG[((size_t)b * L_TOK + r) * D + h * 32 + c] = s;
        }
    }
}

// ---------------------------------------------------------------------------
// K4: out_proj + residual + LayerNorm for 2 token rows.
// grid B*5 = 320, 256 threads (thread = output column).
// w = out_w + l*256*256 ; bias = out_b + l*256 ; lnw/lnb = ln1 + l*256
// ---------------------------------------------------------------------------
__global__ __launch_bounds__(256) void pln_kernel(
    const float* __restrict__ aoG, const float* __restrict__ xres,
    const float* __restrict__ w, const float* __restrict__ bias,
    const float* __restrict__ lnw, const float* __restrict__ lnb,
    float* __restrict__ xout)
{
    const int blk = blockIdx.x;
    const int b = blk / 5;
    const int r0 = (blk - 5 * b) * 2;
    const int tid = threadIdx.x;

    __shared__ float ao2[2 * D];
    __shared__ float red[16];

    ao2[tid]       = aoG[((size_t)b * L_TOK + r0) * D + tid];
    ao2[D + tid]   = aoG[((size_t)b * L_TOK + r0 + 1) * D + tid];
    __syncthreads();

    const float4* a0 = reinterpret_cast<const float4*>(ao2);
    const float4* a1 = reinterpret_cast<const float4*>(ao2 + D);
    const float4* w4 = reinterpret_cast<const float4*>(w + (size_t)tid * D);
    float acc0 = 0.f, acc1 = 0.f;
    #pragma unroll 4
    for (int k4 = 0; k4 < D / 4; k4++) {
        float4 wv = w4[k4];
        float4 v0 = a0[k4], v1 = a1[k4];
        acc0 += wv.x * v0.x + wv.y * v0.y + wv.z * v0.z + wv.w * v0.w;
        acc1 += wv.x * v1.x + wv.y * v1.y + wv.z * v1.z + wv.w * v1.w;
    }
    float bb = bias[tid];
    float v0 = xres[((size_t)b * L_TOK + r0) * D + tid] + acc0 + bb;
    float v1 = xres[((size_t)b * L_TOK + r0 + 1) * D + tid] + acc1 + bb;

    int wid = tid >> 6, lane = tid & 63;
    float s0 = v0, q0 = v0 * v0, s1 = v1, q1 = v1 * v1;
    for (int off = 32; off; off >>= 1) {
        s0 += __shfl_down(s0, off, 64); q0 += __shfl_down(q0, off, 64);
        s1 += __shfl_down(s1, off, 64); q1 += __shfl_down(q1, off, 64);
    }
    if (lane == 0) { red[wid] = s0; red[4 + wid] = q0; red[8 + wid] = s1; red[12 + wid] = q1; }
    __syncthreads();
    float sum0 = red[0] + red[1] + red[2] + red[3];
    float sq0  = red[4] + red[5] + red[6] + red[7];
    float sum1 = red[8] + red[9] + red[10] + red[11];
    float sq1  = red[12] + red[13] + red[14] + red[15];
    float m0 = sum0 * (1.f / D), m1 = sum1 * (1.f / D);
    float rs0 = rsqrtf(fmaxf(sq0 * (1.f / D) - m0 * m0, 0.f) + 1e-5f);
    float rs1 = rsqrtf(fmaxf(sq1 * (1.f / D) - m1 * m1, 0.f) + 1e-5f);
    float lw = lnw[tid], lb = lnb[tid];
    xout[((size_t)b * L_TOK + r0) * D + tid]     = (v0 - m0) * rs0 * lw + lb;
    xout[((size_t)b * L_TOK + r0 + 1) * D + tid] = (v1 - m1) * rs1 * lw + lb;
}

// ---------------------------------------------------------------------------
// K5: FF1 (relu) for a 128-col slice of all 10 rows. grid B*4 = 256, 256 thr.
// w = l1w + l*512*256 ; bias = l1b + l*512
// ---------------------------------------------------------------------------
__global__ __launch_bounds__(256) void ff1_kernel(
    const float* __restrict__ xin,
    const float* __restrict__ w, const float* __restrict__ bias,
    float* __restrict__ h1G)
{
    const int blk = blockIdx.x;
    const int b = blk >> 2;
    const int g = blk & 3;
    const int tid = threadIdx.x;

    __shared__ float xsh[L_TOK * D];
    for (int i = tid; i < L_TOK * D; i += 256)
        xsh[i] = xin[(size_t)b * L_TOK * D + i];
    __syncthreads();

    const float4* xsh4 = reinterpret_cast<const float4*>(xsh);
    #pragma unroll
    for (int jj = 0; jj < 5; jj++) {
        int idx = jj * 256 + tid;      // 1280 outputs = 10 rows x 128 cols
        int r = idx >> 7, c = idx & 127;
        int f = g * 128 + c;
        const float4* w4 = reinterpret_cast<const float4*>(w + (size_t)f * D);
        float acc = 0.f;
        #pragma unroll 4
        for (int k4 = 0; k4 < D / 4; k4++) {
            float4 wv = w4[k4];
            float4 xv = xsh4[r * 64 + k4];
            acc += wv.x * xv.x + wv.y * xv.y + wv.z * xv.z + wv.w * xv.w;
        }
        h1G[((size_t)b * L_TOK + r) * FF + f] = fmaxf(acc + bias[f], 0.f);
    }
}

// ---------------------------------------------------------------------------
// K6: FF2 + residual + LayerNorm for 2 token rows. grid B*5 = 320, 256 thr.
// w = l2w + l*256*512 ; bias = l2b + l*256 ; lnw/lnb = ln2 + l*256
// ---------------------------------------------------------------------------
__global__ __launch_bounds__(256) void ff2_kernel(
    const float* __restrict__ h1G, const float* __restrict__ xres,
    const float* __restrict__ w, const float* __restrict__ bias,
    const float* __restrict__ lnw, const float* __restrict__ lnb,
    float* __restrict__ xout)
{
    const int blk = blockIdx.x;
    const int b = blk / 5;
    const int r0 = (blk - 5 * b) * 2;
    const int tid = threadIdx.x;

    __shared__ float h2[2 * FF];
    __shared__ float red[16];

    h2[tid]        = h1G[((size_t)b * L_TOK + r0) * FF + tid];
    h2[256 + tid]  = h1G[((size_t)b * L_TOK + r0) * FF + 256 + tid];
    h2[512 + tid]  = h1G[((size_t)b * L_TOK + r0 + 1) * FF + tid];
    h2[768 + tid]  = h1G[((size_t)b * L_TOK + r0 + 1) * FF + 256 + tid];
    __syncthreads();

    const float4* a0 = reinterpret_cast<const float4*>(h2);
    const float4* a1 = reinterpret_cast<const float4*>(h2 + FF);
    const float4* w4 = reinterpret_cast<const float4*>(w + (size_t)tid * FF);
    float acc0 = 0.f, acc1 = 0.f;
    #pragma unroll 4
    for (int k4 = 0; k4 < FF / 4; k4++) {
        float4 wv = w4[k4];
        float4 v0 = a0[k4], v1 = a1[k4];
        acc0 += wv.x * v0.x + wv.y * v0.y + wv.z * v0.z + wv.w * v0.w;
        acc1 += wv.x * v1.x + wv.y * v1.y + wv.z * v1.z + wv.w * v1.w;
    }
    float bb = bias[tid];
    float v0 = xres[((size_t)b * L_TOK + r0) * D + tid] + acc0 + bb;
    float v1 = xres[((size_t)b * L_TOK + r0 + 1) * D + tid] + acc1 + bb;

    int wid = tid >> 6, lane = tid & 63;
    float s0 = v0, q0 = v0 * v0, s1 = v1, q1 = v1 * v1;
    for (int off = 32; off; off >>= 1) {
        s0 += __shfl_down(s0, off, 64); q0 += __shfl_down(q0, off, 64);
        s1 += __shfl_down(s1, off, 64); q1 += __shfl_down(q1, off, 64);
    }
    if (lane == 0) { red[wid] = s0; red[4 + wid] = q0; red[8 + wid] = s1; red[12 + wid] = q1; }
    __syncthreads();
    float sum0 = red[0] + red[1] + red[2] + red[3];
    float sq0  = red[4] + red[5] + red[6] + red[7];
    float sum1 = red[8] + red[9] + red[10] + red[11];
    float sq1  = red[12] + red[13] + red[14] + red[15];
    float m0 = sum0 * (1.f / D), m1 = sum1 * (1.f / D);
    float rs0 = rsqrtf(fmaxf(sq0 * (1.f / D) - m0 * m0, 0.f) + 1e-5f);
    float rs1 = rsqrtf(fmaxf(sq1 * (1.f / D) - m1 * m1, 0.f) + 1e-5f);
    float lw = lnw[tid], lb = lnb[tid];
    xout[((size_t)b * L_TOK + r0) * D + tid]     = (v0 - m0) * rs0 * lw + lb;
    xout[((size_t)b * L_TOK + r0 + 1) * D + tid] = (v1 - m1) * rs1 * lw + lb;
}

// ---------------------------------------------------------------------------
// K7: masked mean pool + 2-layer classifier. grid B, 1024 threads.
// ---------------------------------------------------------------------------
__global__ __launch_bounds__(1024) void cls_kernel(
    const float* __restrict__ xin, const float* __restrict__ biasG,
    const float* __restrict__ c1w, const float* __restrict__ c1b,
    const float* __restrict__ c2w, const float* __restrict__ c2b,
    float* __restrict__ out)
{
    const int b = blockIdx.x;
    const int tid = threadIdx.x;

    __shared__ float ct[D];
    __shared__ float clsP[1024];
    __shared__ float hbuf[512];
    __shared__ float cls2P[2 * NCLS];
    __shared__ float biasK[16];

    if (tid < L_TOK) biasK[tid] = biasG[b * L_TOK + tid];
    __syncthreads();

    if (tid < D) {
        float len = 0.f, s = 0.f;
        #pragma unroll
        for (int r = 0; r < L_TOK; r++) {
            float v = (biasK[r] == 0.f) ? 1.f : 0.f;
            len += v;
            s += v * xin[(size_t)b * L_TOK * D + r * D + tid];
        }
        ct[tid] = s / fmaxf(len, 1.f);
    }
    __syncthreads();

    {   // cls1: 512 outputs, K split over kh
        int c = tid & 511, kh = tid >> 9;
        const float4* w4 = reinterpret_cast<const float4*>(c1w + (size_t)c * D + kh * 128);
        const float4* ct4 = reinterpret_cast<const float4*>(ct + kh * 128);
        float acc = 0.f;
        #pragma unroll 4
        for (int k4 = 0; k4 < 32; k4++) {
            float4 wv = w4[k4];
            float4 xv = ct4[k4];
            acc += wv.x * xv.x + wv.y * xv.y + wv.z * xv.z + wv.w * xv.w;
        }
        clsP[kh * 512 + c] = acc;
    }
    __syncthreads();
    if (tid < 512) hbuf[tid] = fmaxf(clsP[tid] + clsP[512 + tid] + c1b[tid], 0.f);
    __syncthreads();

    {   // cls2: 396 outputs, K split over kh
        int o = tid & 511, kh = tid >> 9;
        if (o < NCLS) {
            const float4* w4 = reinterpret_cast<const float4*>(c2w + (size_t)o * FF + kh * 256);
            const float4* h4 = reinterpret_cast<const float4*>(hbuf + kh * 256);
            float acc = 0.f;
            #pragma unroll 4
            for (int k4 = 0; k4 < 64; k4++) {
                float4 wv = w4[k4];
                float4 hv = h4[k4];
                acc += wv.x * hv.x + wv.y * hv.y + wv.z * hv.z + wv.w * hv.w;
            }
            cls2P[kh * NCLS + o] = acc;
        }
    }
    __syncthreads();
    if (tid < NCLS) out[(size_t)b * NCLS + tid] = cls2P[tid] + cls2P[NCLS + tid] + c2b[tid];
}

// ---------------------------------------------------------------------------
extern "C" void kernel_launch(void* const* d_in, const int* in_sizes, int n_in,
                              void* d_out, int out_size, void* d_ws, size_t ws_size,
                              hipStream_t stream)
{
    const float* pred = (const float*)d_in[0];
    const float* hs   = (const float*)d_in[1];
    const float* f0   = (const float*)d_in[2];
    const float* f1   = (const float*)d_in[3];
    const float* f2   = (const float*)d_in[4];
    const float* f3   = (const float*)d_in[5];
    const float* ipw  = (const float*)d_in[6];
    const float* ipb  = (const float*)d_in[7];
    const float* inw  = (const float*)d_in[8];
    const float* inb  = (const float*)d_in[9];
    const float* ow   = (const float*)d_in[10];
    const float* ob   = (const float*)d_in[11];
    const float* l1w  = (const float*)d_in[12];
    const float* l1b  = (const float*)d_in[13];
    const float* l2w  = (const float*)d_in[14];
    const float* l2b  = (const float*)d_in[15];
    const float* ln1w = (const float*)d_in[16];
    const float* ln1b = (const float*)d_in[17];
    const float* ln2w = (const float*)d_in[18];
    const float* ln2b = (const float*)d_in[19];
    const float* c1w  = (const float*)d_in[20];
    const float* c1b  = (const float*)d_in[21];
    const float* c2w  = (const float*)d_in[22];
    const float* c2b  = (const float*)d_in[23];

    float* ws = (float*)d_ws;
    float* pooled = ws;                       //  65536
    float* xA     = pooled + B * 4 * D;       // 163840
    float* xB     = xA + B * L_TOK * D;       // 163840
    float* aoG    = xB + B * L_TOK * D;       // 163840
    float* h1G    = aoG + B * L_TOK * D;      // 327680
    float* biasG  = h1G + B * L_TOK * FF;     //    640

    pool_kernel<<<4 * B * D, 256, 0, stream>>>(f0, f1, f2, f3, pooled);
    prologue_kernel<<<B, 1024, 0, stream>>>(pred, hs, pooled, ipw, ipb, xA, biasG);

    for (int l = 0; l < NLAYERS; l++) {
        const float* xin = (l == 0) ? xA : xA;   // xA is layer input (ping-pong returns to xA)
        attn_kernel<<<B * NHEAD, 256, 0, stream>>>(
            xin, biasG, inw + (size_t)l * 768 * D, inb + (size_t)l * 768, aoG);
        pln_kernel<<<B * 5, 256, 0, stream>>>(
            aoG, xin, ow + (size_t)l * D * D, ob + (size_t)l * D,
            ln1w + (size_t)l * D, ln1b + (size_t)l * D, xB);
        ff1_kernel<<<B * 4, 256, 0, stream>>>(
            xB, l1w + (size_t)l * FF * D, l1b + (size_t)l * FF, h1G);
        ff2_kernel<<<B * 5, 256, 0, stream>>>(
            h1G, xB, l2w + (size_t)l * D * FF, l2b + (size_t)l * D,
            ln2w + (size_t)l * D, ln2b + (size_t)l * D, xA);
    }

    cls_kernel<<<B, 1024, 0, stream>>>(xA, biasG, c1w, c1b, c2w, c2b, (float*)d_out);
}

// Round 5
// 356.413 us; speedup vs baseline: 2.1232x; 1.4894x over previous
//
#include <hip/hip_runtime.h>
#include <math.h>

#define NB 64
#define NQ 300
#define NP 6
#define ND 256
#define NF 512
#define NCL 396
#define NT 10

typedef float f4 __attribute__((ext_vector_type(4)));

__device__ __forceinline__ float dot4(f4 a, f4 b) {
    return a.x * b.x + a.y * b.y + a.z * b.z + a.w * b.w;
}
__device__ __forceinline__ float wred(float s) {
    #pragma unroll
    for (int o = 32; o; o >>= 1) s += __shfl_down(s, o, 64);
    return s;
}

// ---------------------------------------------------------------------------
// K1: blocks 0..63  -> per-class masked mean pool (tokens rows 0..5) + bias
//     blocks 64+    -> feat global-average-pool rows (nontemporal loads so the
//                      800MB stream does not evict transformer weights).
// ---------------------------------------------------------------------------
__global__ __launch_bounds__(256) void pool_cls_kernel(
    const float* __restrict__ pred, const float* __restrict__ hs,
    const float* __restrict__ f0, const float* __restrict__ f1,
    const float* __restrict__ f2, const float* __restrict__ f3,
    float* __restrict__ pooled, float* __restrict__ tokG,
    float* __restrict__ biasW)
{
    const int bid = blockIdx.x;
    const int tid = threadIdx.x;
    __shared__ float shm[1824];   // maskL[1800] | counts[8] (cls) ; red[4] (pool)

    if (bid < NB) {
        // ---------------- cls-pool for b = bid (proven R1 code) ----------------
        const int b = bid;
        float* maskL = shm;
        float* countsL = shm + 1800;
        for (int i = tid; i < NQ * NP; i += 256) {
            float x = pred[(size_t)b * NQ * NP + i];
            float sg = 1.f / (1.f + expf(-x));
            maskL[i] = (sg > 0.3f) ? 1.f : 0.f;
        }
        __syncthreads();
        if (tid < NP) {
            float c = 0.f;
            for (int q = 0; q < NQ; q++) c += maskL[q * NP + tid];
            countsL[tid] = c;
        }
        __syncthreads();
        float acc[NP] = {0.f, 0.f, 0.f, 0.f, 0.f, 0.f};
        const float* hsb = hs + (size_t)b * NQ * ND + tid;
        for (int q = 0; q < NQ; q++) {
            float h = hsb[(size_t)q * ND];
            #pragma unroll
            for (int p = 0; p < NP; p++) acc[p] += maskL[q * NP + p] * h;
        }
        bool anyv = false;
        #pragma unroll
        for (int p = 0; p < NP; p++) anyv = anyv || (countsL[p] > 0.f);
        #pragma unroll
        for (int p = 0; p < NP; p++) {
            float cm = acc[p] / fmaxf(countsL[p], 1.f);
            if (p == 0 && !anyv) cm = hs[(size_t)b * NQ * ND + tid];
            tokG[(size_t)b * 1536 + p * ND + tid] = cm;
        }
        if (tid < 16) {
            float bv = 0.f;
            if (tid < NP) {
                bool v = countsL[tid] > 0.f;
                if (tid == 0 && !anyv) v = true;
                bv = v ? 0.f : -1e30f;
            }
            biasW[b * 16 + tid] = bv;
        }
        return;
    }

    // ---------------- pooling row = bid - 64 ----------------
    const int row = bid - NB;
    const int scale = row >> 14;
    const int rr = row & 16383;
    const int b = rr >> 8;
    const int d = rr & 255;
    const float* src;
    int n;
    switch (scale) {
        case 0: src = f0; n = 96 * 96; break;
        case 1: src = f1; n = 48 * 48; break;
        case 2: src = f2; n = 24 * 24; break;
        default: src = f3; n = 12 * 12; break;
    }
    const f4* p4 = reinterpret_cast<const f4*>(src + ((size_t)b * ND + d) * (size_t)n);
    int n4 = n >> 2;
    float s = 0.f;
    for (int i = tid; i < n4; i += 256) {
        f4 v = __builtin_nontemporal_load(&p4[i]);
        s += v.x + v.y + v.z + v.w;
    }
    s = wred(s);
    int wid = tid >> 6, lane = tid & 63;
    if (lane == 0) shm[wid] = s;
    __syncthreads();
    if (tid == 0) {
        float t = shm[0] + shm[1] + shm[2] + shm[3];
        pooled[((size_t)b * 4 + scale) * ND + d] = t / (float)n;
    }
}

// ---------------------------------------------------------------------------
// K2: fused per-batch {img proj + 2-layer transformer + pool + classifier}.
// 64 blocks x 512 threads. Column-split GEMMs: thread owns output column,
// 10-row register accumulator; K-split across thread halves for 256-col GEMMs.
// ---------------------------------------------------------------------------
__global__ __launch_bounds__(512) void xform_kernel(
    const float* __restrict__ pooled, const float* __restrict__ tokG,
    const float* __restrict__ biasW,
    const float* __restrict__ ipw, const float* __restrict__ ipb,
    const float* __restrict__ inw, const float* __restrict__ inb,
    const float* __restrict__ ow, const float* __restrict__ ob,
    const float* __restrict__ l1w, const float* __restrict__ l1b,
    const float* __restrict__ l2w, const float* __restrict__ l2b,
    const float* __restrict__ n1w, const float* __restrict__ n1b,
    const float* __restrict__ n2w, const float* __restrict__ n2b,
    const float* __restrict__ c1w, const float* __restrict__ c1b,
    const float* __restrict__ c2w, const float* __restrict__ c2b,
    float* __restrict__ out)
{
    const int b = blockIdx.x;
    const int tid = threadIdx.x;
    const int lane = tid & 63;
    const int wv = tid >> 6;

    __shared__ __align__(16) float xs[NT * ND];    // 2560 current x
    __shared__ __align__(16) float qs[NT * 768];   // 7680 qkv / ff2 partials
    __shared__ __align__(16) float xr[NT * ND];    // 2560 residual / ct
    __shared__ __align__(16) float ao[NT * ND];    // 2560 attn out
    __shared__ __align__(16) float tmp[NT * NF];   // 5120 pld / outproj partials / h1 / hb
    __shared__ float sc[800];
    __shared__ float stats[32];
    __shared__ float biasK[16];

    float* pld = tmp;

    // stage tokens rows 0..5, pooled, bias
    for (int i = tid; i < 1536; i += 512) xs[i] = tokG[(size_t)b * 1536 + i];
    for (int i = tid; i < 1024; i += 512) pld[i] = pooled[(size_t)b * 1024 + i];
    if (tid < 16) biasK[tid] = biasW[b * 16 + tid];
    __syncthreads();

    const f4* xs4 = reinterpret_cast<const f4*>(xs);

    // ---- img tokens -> xs rows 6..9 (1024 outputs, 2/thread) ----
    for (int idx = tid; idx < 1024; idx += 512) {
        int i = idx >> 8, c = idx & 255;
        const f4* w4 = reinterpret_cast<const f4*>(ipw + ((size_t)i * ND + c) * ND);
        const f4* p4 = reinterpret_cast<const f4*>(pld + i * ND);
        float acc = 0.f;
        #pragma unroll 4
        for (int k4 = 0; k4 < 64; k4++) acc += dot4(w4[k4], p4[k4]);
        xs[(6 + i) * ND + c] = acc + ipb[i * ND + c];
    }
    __syncthreads();

    for (int l = 0; l < 2; l++) {
        // ---- (a) QKV: 768 cols, thread=col, acc[10] ----
        for (int c = tid; c < 768; c += 512) {
            const f4* w4 = reinterpret_cast<const f4*>(inw + ((size_t)l * 768 + c) * ND);
            float acc[NT];
            #pragma unroll
            for (int r = 0; r < NT; r++) acc[r] = 0.f;
            #pragma unroll 2
            for (int k4 = 0; k4 < 64; k4++) {
                f4 wvv = w4[k4];
                #pragma unroll
                for (int r = 0; r < NT; r++) acc[r] += dot4(wvv, xs4[r * 64 + k4]);
            }
            float bb = inb[l * 768 + c];
            #pragma unroll
            for (int r = 0; r < NT; r++) qs[r * 768 + c] = acc[r] + bb;
        }
        __syncthreads();

        // ---- (b) scores + bias ----
        for (int t = tid; t < 800; t += 512) {
            int h = t / 100, rem = t - 100 * h;
            int qr = rem / 10, kr = rem - 10 * qr;
            const float* qp = &qs[qr * 768 + h * 32];
            const float* kp = &qs[kr * 768 + ND + h * 32];
            float s = 0.f;
            #pragma unroll
            for (int dh = 0; dh < 32; dh++) s += qp[dh] * kp[dh];
            sc[t] = s * 0.17677669529663687f + biasK[kr];
        }
        __syncthreads();

        // ---- (c) softmax (80 rows) ----
        if (tid < 80) {
            float* row = &sc[tid * 10];
            float m = row[0];
            #pragma unroll
            for (int k = 1; k < 10; k++) m = fmaxf(m, row[k]);
            float ss = 0.f;
            #pragma unroll
            for (int k = 0; k < 10; k++) { float e = expf(row[k] - m); row[k] = e; ss += e; }
            float inv = 1.f / ss;
            #pragma unroll
            for (int k = 0; k < 10; k++) row[k] *= inv;
        }
        __syncthreads();

        // ---- (d) attn @ V -> ao (2560 outputs, 5/thread) ----
        for (int idx = tid; idx < NT * ND; idx += 512) {
            int r = idx >> 8, col = idx & 255, h = col >> 5;
            float s = 0.f;
            #pragma unroll
            for (int kr = 0; kr < 10; kr++)
                s += sc[h * 100 + r * 10 + kr] * qs[kr * 768 + 512 + col];
            ao[idx] = s;
        }
        __syncthreads();

        // ---- (e) out_proj (K-split over 2 halves) + residual -> xr ----
        {
            int kh = tid >> 8, c = tid & 255;
            const f4* w4 = reinterpret_cast<const f4*>(ow + ((size_t)l * ND + c) * ND + kh * 128);
            const f4* ao4 = reinterpret_cast<const f4*>(ao);
            float acc[NT];
            #pragma unroll
            for (int r = 0; r < NT; r++) acc[r] = 0.f;
            #pragma unroll 2
            for (int k4 = 0; k4 < 32; k4++) {
                f4 wvv = w4[k4];
                #pragma unroll
                for (int r = 0; r < NT; r++) acc[r] += dot4(wvv, ao4[r * 64 + kh * 32 + k4]);
            }
            #pragma unroll
            for (int r = 0; r < NT; r++) tmp[kh * 2560 + r * ND + c] = acc[r];
        }
        __syncthreads();
        for (int i = tid; i < NT * ND; i += 512)
            xr[i] = xs[i] + tmp[i] + tmp[2560 + i] + ob[l * ND + (i & 255)];
        __syncthreads();

        // ---- (f) LN1: xr -> xs ----
        for (int r = wv; r < NT; r += 8) {
            float v0 = xr[r * ND + lane], v1 = xr[r * ND + 64 + lane];
            float v2 = xr[r * ND + 128 + lane], v3 = xr[r * ND + 192 + lane];
            float s = wred(v0 + v1 + v2 + v3);
            float q = wred(v0 * v0 + v1 * v1 + v2 * v2 + v3 * v3);
            if (lane == 0) {
                float m = s * (1.f / ND);
                stats[r] = m;
                stats[16 + r] = rsqrtf(fmaxf(q * (1.f / ND) - m * m, 0.f) + 1e-5f);
            }
        }
        __syncthreads();
        for (int i = tid; i < NT * ND; i += 512) {
            int r = i >> 8, c = i & 255;
            xs[i] = (xr[i] - stats[r]) * stats[16 + r] * n1w[l * ND + c] + n1b[l * ND + c];
        }
        __syncthreads();

        // ---- (g) FF1: 512 cols = tid, relu -> tmp (h1) ----
        {
            int c = tid;
            const f4* w4 = reinterpret_cast<const f4*>(l1w + ((size_t)l * NF + c) * ND);
            float acc[NT];
            #pragma unroll
            for (int r = 0; r < NT; r++) acc[r] = 0.f;
            #pragma unroll 2
            for (int k4 = 0; k4 < 64; k4++) {
                f4 wvv = w4[k4];
                #pragma unroll
                for (int r = 0; r < NT; r++) acc[r] += dot4(wvv, xs4[r * 64 + k4]);
            }
            float bb = l1b[l * NF + c];
            __syncthreads();   // tmp (outproj partials) dead before overwrite
            #pragma unroll
            for (int r = 0; r < NT; r++) tmp[r * NF + c] = fmaxf(acc[r] + bb, 0.f);
        }
        __syncthreads();

        // ---- (h) FF2 (K-split over 2 halves of 256) + residual -> xr ----
        {
            int kh = tid >> 8, c = tid & 255;
            const f4* w4 = reinterpret_cast<const f4*>(l2w + ((size_t)l * ND + c) * NF + kh * 256);
            const f4* h14 = reinterpret_cast<const f4*>(tmp);
            float acc[NT];
            #pragma unroll
            for (int r = 0; r < NT; r++) acc[r] = 0.f;
            #pragma unroll 2
            for (int k4 = 0; k4 < 64; k4++) {
                f4 wvv = w4[k4];
                #pragma unroll
                for (int r = 0; r < NT; r++) acc[r] += dot4(wvv, h14[r * 128 + kh * 64 + k4]);
            }
            #pragma unroll
            for (int r = 0; r < NT; r++) qs[kh * 2560 + r * ND + c] = acc[r];
        }
        __syncthreads();
        for (int i = tid; i < NT * ND; i += 512)
            xr[i] = xs[i] + qs[i] + qs[2560 + i] + l2b[l * ND + (i & 255)];
        __syncthreads();

        // ---- (i) LN2: xr -> xs ----
        for (int r = wv; r < NT; r += 8) {
            float v0 = xr[r * ND + lane], v1 = xr[r * ND + 64 + lane];
            float v2 = xr[r * ND + 128 + lane], v3 = xr[r * ND + 192 + lane];
            float s = wred(v0 + v1 + v2 + v3);
            float q = wred(v0 * v0 + v1 * v1 + v2 * v2 + v3 * v3);
            if (lane == 0) {
                float m = s * (1.f / ND);
                stats[r] = m;
                stats[16 + r] = rsqrtf(fmaxf(q * (1.f / ND) - m * m, 0.f) + 1e-5f);
            }
        }
        __syncthreads();
        for (int i = tid; i < NT * ND; i += 512) {
            int r = i >> 8, c = i & 255;
            xs[i] = (xr[i] - stats[r]) * stats[16 + r] * n2w[l * ND + c] + n2b[l * ND + c];
        }
        __syncthreads();
    }

    // ---- masked mean pool -> xr[0..256) ----
    if (tid < ND) {
        float len = 0.f, s = 0.f;
        #pragma unroll
        for (int r = 0; r < NT; r++) {
            float v = (biasK[r] == 0.f) ? 1.f : 0.f;
            len += v;
            s += v * xs[r * ND + tid];
        }
        xr[tid] = s / fmaxf(len, 1.f);
    }
    __syncthreads();

    // ---- cls1: 512 outputs = tid ----
    {
        const f4* w4 = reinterpret_cast<const f4*>(c1w + (size_t)tid * ND);
        const f4* ct4 = reinterpret_cast<const f4*>(xr);
        float acc = 0.f;
        #pragma unroll 4
        for (int k4 = 0; k4 < 64; k4++) acc += dot4(w4[k4], ct4[k4]);
        float hb = fmaxf(acc + c1b[tid], 0.f);
        __syncthreads();   // tmp (h1) dead
        tmp[tid] = hb;
    }
    __syncthreads();

    // ---- cls2: 396 outputs ----
    if (tid < NCL) {
        const f4* w4 = reinterpret_cast<const f4*>(c2w + (size_t)tid * NF);
        const f4* h4 = reinterpret_cast<const f4*>(tmp);
        float acc = 0.f;
        #pragma unroll 4
        for (int k4 = 0; k4 < 128; k4++) acc += dot4(w4[k4], h4[k4]);
        out[(size_t)b * NCL + tid] = acc + c2b[tid];
    }
}

// ---------------------------------------------------------------------------
extern "C" void kernel_launch(void* const* d_in, const int* in_sizes, int n_in,
                              void* d_out, int out_size, void* d_ws, size_t ws_size,
                              hipStream_t stream)
{
    const float* pred = (const float*)d_in[0];
    const float* hs   = (const float*)d_in[1];
    const float* f0   = (const float*)d_in[2];
    const float* f1   = (const float*)d_in[3];
    const float* f2   = (const float*)d_in[4];
    const float* f3   = (const float*)d_in[5];
    const float* ipw  = (const float*)d_in[6];
    const float* ipb  = (const float*)d_in[7];
    const float* inw  = (const float*)d_in[8];
    const float* inb  = (const float*)d_in[9];
    const float* ow   = (const float*)d_in[10];
    const float* ob   = (const float*)d_in[11];
    const float* l1w  = (const float*)d_in[12];
    const float* l1b  = (const float*)d_in[13];
    const float* l2w  = (const float*)d_in[14];
    const float* l2b  = (const float*)d_in[15];
    const float* ln1w = (const float*)d_in[16];
    const float* ln1b = (const float*)d_in[17];
    const float* ln2w = (const float*)d_in[18];
    const float* ln2b = (const float*)d_in[19];
    const float* c1w  = (const float*)d_in[20];
    const float* c1b  = (const float*)d_in[21];
    const float* c2w  = (const float*)d_in[22];
    const float* c2b  = (const float*)d_in[23];

    float* ws = (float*)d_ws;
    float* pooled = ws;                    // 65536
    float* tokG   = pooled + NB * 4 * ND;  // 98304 (B*6*256)
    float* biasW  = tokG + NB * 1536;      // 1024

    pool_cls_kernel<<<NB + 4 * NB * ND, 256, 0, stream>>>(
        pred, hs, f0, f1, f2, f3, pooled, tokG, biasW);
    xform_kernel<<<NB, 512, 0, stream>>>(
        pooled, tokG, biasW, ipw, ipb, inw, inb, ow, ob, l1w, l1b, l2w, l2b,
        ln1w, ln1b, ln2w, ln2b, c1w, c1b, c2w, c2b, (float*)d_out);
}